// Round 3
// baseline (279.160 us; speedup 1.0000x reference)
//
#include <hip/hip_runtime.h>

// Projector: out[n,p,o] = x@Wd^T + bd + softmax_l((x@W1^T)·(t@W2^T)^T) @ (t@W3^T + b3)
// N=16, HW=3136, L=64, C_IN=256, C_OUT=512, D=256. fp32 in/out.
// R7: residency attack via accumulator halving (no work duplication).
//   R6 combined regfile use ~136 (64 VGPR + 72 AGPR) > 128 cliff -> 2 waves/
//   SIMD -> ONE 8-wave block/CU -> serial phase chain (all pipes <=24%).
//   Split o in time: acc[4][2] per half (~104 combined regs) -> 4 waves/SIMD
//   -> 2 blocks/CU; block A's stage/stores overlap block B's MFMA.
//   - GEMM4-h0 fused into GEMM2 loop (shares xs A-frags, fills mtf latency).
//   - epilogue scratch in dedicated LDS (xs stays live for h1); 128B-aligned
//     float4 store bursts (one full cache line per wave-row-half).
//   - LDS 62,464 B => 2 blocks/CU = 125 KB.
// Phases: stage -> B1 -> GEMM2+GEMM4h0 -> partials -> B2 -> merge/aw -> B3
//   -> GEMM3h0 -> epi h0 -> GEMM4h1+GEMM3h1 -> epi h1. 4 barriers.

typedef unsigned short u16;
using half8 = __attribute__((ext_vector_type(8))) _Float16;
using f32x4 = __attribute__((ext_vector_type(4))) float;

__device__ __forceinline__ u16 f2h(float f) {
  _Float16 h = (_Float16)f;            // RNE
  union { _Float16 h; u16 u; } cv; cv.h = h;
  return cv.u;
}

__device__ __forceinline__ f32x4 mfma16(half8 a, half8 b, f32x4 c) {
  return __builtin_amdgcn_mfma_f32_16x16x32_f16(a, b, c, 0, 0, 0);
}

// ---------------------------------------------------------------------------
// K0: reblock W3/Wd/t to fragment-linear f16, and compute Gt = (W1^T W2)^T
// in f32 (Gt[c,e] = sum_d W1[d,c]*W2[d,e]), rounded once to f16 FL.
// FL: flat(row,k) = ((row/16)*8 + k/32)*512 + ((k/8)%4)*128 + (row%16)*8 + (k%8)
// ---------------------------------------------------------------------------
__global__ __launch_bounds__(256) void prep_kernel(
    const float* __restrict__ W1, const float* __restrict__ W2,
    const float* __restrict__ W3, const float* __restrict__ Wd,
    const float* __restrict__ t,
    u16* __restrict__ W3f, u16* __restrict__ Wdf, u16* __restrict__ tf,
    u16* __restrict__ Gtf) {
  int b = blockIdx.x, k = threadIdx.x;
  if (b < 2048) {
    const float* src; u16* dst; int row;
    if (b < 512)       { src = W3; dst = W3f; row = b; }
    else if (b < 1024) { src = Wd; dst = Wdf; row = b - 512; }
    else               { src = t;  dst = tf;  row = b - 1024; }
    float v = src[(size_t)row*256 + k];
    int flat = ((row >> 4)*8 + (k >> 5))*512 + ((k >> 3) & 3)*128 + (row & 15)*8 + (k & 7);
    dst[flat] = f2h(v);
  } else {
    // Gt row c = b-2048 (uniform per block); thread k = e (coalesced W2 reads)
    int c = b - 2048;
    float g = 0.f;
    #pragma unroll 16
    for (int d = 0; d < 256; ++d)
      g = fmaf(W1[d*256 + c], W2[d*256 + k], g);
    int flat = ((c >> 4)*8 + (k >> 5))*512 + ((k >> 3) & 3)*128 + (c & 15)*8 + (k & 7);
    Gtf[flat] = f2h(g);
  }
}

// ---------------------------------------------------------------------------
// K1: per-n small GEMMs, all operands FL, outputs written FL.
// blocks 0..63:   Mt[n,l,c] = sum_e t[n,l,e]*Gt[c,e]  -> mtf (rows=l, K=c=256)
// blocks 64..191: t3[n,o,l] = t@W3^T + b3             -> t3f (rows=o, K=l=64)
// ---------------------------------------------------------------------------
__global__ __launch_bounds__(256) void mt_t3_kernel(
    const u16* __restrict__ tf, const u16* __restrict__ Gtf,
    const u16* __restrict__ W3f, const float* __restrict__ b3,
    u16* __restrict__ mtf, u16* __restrict__ t3f) {
  const int tid = threadIdx.x, w = tid >> 6, lane = tid & 63;
  const int quad = lane >> 4, l16 = lane & 15;
  const int b = blockIdx.x;

  if (b < 64) {
    const int n = b >> 2, eb = b & 3;      // eb = c-quarter
    const int gc = eb*4 + w;               // c-row group (c0 = eb*64 + w*16)
    f32x4 acc[4];
    #pragma unroll
    for (int mt = 0; mt < 4; ++mt) acc[mt] = (f32x4){0.f, 0.f, 0.f, 0.f};
    #pragma unroll
    for (int kc = 0; kc < 8; ++kc) {
      half8 bf = *(const half8*)(Gtf + (gc*8 + kc)*512 + lane*8);
      #pragma unroll
      for (int mt = 0; mt < 4; ++mt) {
        half8 a = *(const half8*)(tf + ((n*4 + mt)*8 + kc)*512 + lane*8);
        acc[mt] = mfma16(a, bf, acc[mt]);
      }
    }
    // value at (l = mt*16+quad*4+r, c = eb*64+w*16+l16); write FL for GEMM2
    #pragma unroll
    for (int mt = 0; mt < 4; ++mt)
      #pragma unroll
      for (int r = 0; r < 4; ++r) {
        int flat = ((n*4 + mt)*8 + eb*2 + (w >> 1))*512
                 + ((w & 1)*2 + (l16 >> 3))*128 + (quad*4 + r)*8 + (l16 & 7);
        mtf[flat] = f2h(acc[mt][r]);
      }
  } else {
    const int b2 = b - 64;
    const int n = b2 >> 3, ob = b2 & 7;
    const int gW3 = ob*4 + w;          // o-row group (o0 = ob*64 + w*16)
    f32x4 acc[4];
    #pragma unroll
    for (int nt = 0; nt < 4; ++nt) acc[nt] = (f32x4){0.f, 0.f, 0.f, 0.f};
    #pragma unroll
    for (int kc = 0; kc < 8; ++kc) {
      half8 a = *(const half8*)(W3f + (gW3*8 + kc)*512 + lane*8);
      #pragma unroll
      for (int nt = 0; nt < 4; ++nt) {
        half8 bf = *(const half8*)(tf + ((n*4 + nt)*8 + kc)*512 + lane*8);
        acc[nt] = mfma16(a, bf, acc[nt]);
      }
    }
    // value at (o = ob*64+w*16+quad*4+r, l = nt*16+l16); write FL for GEMM3
    #pragma unroll
    for (int nt = 0; nt < 4; ++nt)
      #pragma unroll
      for (int r = 0; r < 4; ++r) {
        int o = ob*64 + w*16 + quad*4 + r;
        int flat = ((n*32 + ob*4 + w)*2 + (nt >> 1))*512
                 + ((nt & 1)*2 + (l16 >> 3))*128 + (quad*4 + r)*8 + (l16 & 7);
        t3f[flat] = f2h(acc[nt][r] + b3[o]);
      }
  }
}

// ---------------------------------------------------------------------------
// K2: main fused kernel. grid 784 = 16 n * 49 row-tiles of 64; 512 threads.
// smem carve (62,464 B):
//   [0, 33792):       xs 64 x 264 u16           (live until GEMM4-h1)
//   [33792, 43008):   aw 64 x 72 u16            (live until GEMM3-h1)
//   [43008, 44032):   parts 64 x 2 x {mx,ps} f32
//   [44032, 62464):   epi scratch, 8 waves x 16 x 36 f32 (wave-private)
// 4 barriers. Regs ~104 combined -> 4 waves/SIMD -> 2 blocks/CU (125 KB LDS).
// ---------------------------------------------------------------------------
__global__ __launch_bounds__(512, 4) void main_kernel(
    const float* __restrict__ x, const u16* __restrict__ Wdf,
    const u16* __restrict__ mtf, const u16* __restrict__ t3f,
    const float* __restrict__ bd, float* __restrict__ out) {
  __shared__ __attribute__((aligned(16))) char smem[62464];
  u16* xs = (u16*)smem;                      // 64 x 264
  u16* aw = (u16*)(smem + 33792);            // 64 x 72
  float* parts = (float*)(smem + 43008);     // 64 x 2 x {mx, ps}
  float* scb = (float*)(smem + 44032);       // 8 x (16 x 36) f32

  const int bid = blockIdx.x;
  const int n  = bid / 49;
  const int pt = bid - n*49;
  const int m0 = pt * 64;
  const int tid = threadIdx.x, w = tid >> 6, lane = tid & 63;
  const int quad = lane >> 4, l16 = lane & 15;
  const int rg = w & 3;        // GEMM2 row-group (rows rg*16..rg*16+15)
  const int lp = w >> 2;       // GEMM2 l-pair (l-groups lp*2, lp*2+1)

  float bias[4];
  #pragma unroll
  for (int ot = 0; ot < 4; ++ot) bias[ot] = bd[w*64 + ot*16 + l16];

  // ---- stage x tile: 64x256 fp32 -> f16 LDS (coalesced float4) ----
  {
    const float4* xg = (const float4*)(x + (size_t)(n*3136 + m0)*256);
    #pragma unroll
    for (int it = 0; it < 8; ++it) {
      int idx = it*512 + tid;
      int r = idx >> 6, c4 = idx & 63;
      float4 v = xg[idx];
      ushort4 u;
      u.x = f2h(v.x); u.y = f2h(v.y); u.z = f2h(v.z); u.w = f2h(v.w);
      *(ushort4*)(&xs[r*264 + c4*4]) = u;
    }
  }
  __syncthreads();                                             // B1

  // ---- GEMM2 (a = xs@Mt^T, 16 rows x 32 l per wave) fused with GEMM4-h0
  //      (xs@Wd^T, o-cols w*64..w*64+31) -- shared xs A-fragments. ----
  f32x4 acc2[2];
  acc2[0] = (f32x4){0.f, 0.f, 0.f, 0.f};
  acc2[1] = (f32x4){0.f, 0.f, 0.f, 0.f};
  f32x4 acc[4][2];
  #pragma unroll
  for (int mt = 0; mt < 4; ++mt)
    #pragma unroll
    for (int ot = 0; ot < 2; ++ot) acc[mt][ot] = (f32x4){0.f, 0.f, 0.f, 0.f};
  #pragma unroll
  for (int kc = 0; kc < 8; ++kc) {
    half8 a[4];
    #pragma unroll
    for (int mt = 0; mt < 4; ++mt)
      a[mt] = *(const half8*)(&xs[(mt*16 + l16)*264 + kc*32 + quad*8]);
    #pragma unroll
    for (int j = 0; j < 2; ++j) {
      half8 bf = *(const half8*)(mtf + ((size_t)(n*4 + lp*2 + j)*8 + kc)*512 + lane*8);
      acc2[j] = mfma16(a[rg], bf, acc2[j]);
    }
    #pragma unroll
    for (int ot = 0; ot < 2; ++ot) {
      half8 bf = *(const half8*)(Wdf + ((size_t)(w*4 + ot)*8 + kc)*512 + lane*8);
      #pragma unroll
      for (int mt = 0; mt < 4; ++mt) acc[mt][ot] = mfma16(a[mt], bf, acc[mt][ot]);
    }
  }

  // ---- softmax partials over this wave's 32 l-cols ----
  float mx_[4], ps_[4], e0_[4], e1_[4];
  #pragma unroll
  for (int r = 0; r < 4; ++r) {
    float s0 = acc2[0][r], s1 = acc2[1][r];
    float mx = fmaxf(s0, s1);
    #pragma unroll
    for (int off = 8; off >= 1; off >>= 1) mx = fmaxf(mx, __shfl_xor(mx, off, 64));
    float e0 = __expf(s0 - mx), e1 = __expf(s1 - mx);
    float ps = e0 + e1;
    #pragma unroll
    for (int off = 8; off >= 1; off >>= 1) ps += __shfl_xor(ps, off, 64);
    mx_[r] = mx; ps_[r] = ps; e0_[r] = e0; e1_[r] = e1;
    if (l16 == 0) {
      int row = rg*16 + quad*4 + r;
      parts[(row*2 + lp)*2]     = mx;
      parts[(row*2 + lp)*2 + 1] = ps;
    }
  }
  __syncthreads();                                             // B2

  // ---- combine partials (online-softmax merge), write aw ----
  #pragma unroll
  for (int r = 0; r < 4; ++r) {
    int row = rg*16 + quad*4 + r;
    float mxo = parts[(row*2 + (1 - lp))*2];
    float pso = parts[(row*2 + (1 - lp))*2 + 1];
    float g  = fmaxf(mx_[r], mxo);
    float sA = __expf(mx_[r] - g), sB = __expf(mxo - g);
    float inv = 1.0f / (ps_[r]*sA + pso*sB);
    float scl = sA * inv;
    aw[row*72 + (lp*2)*16 + l16]     = f2h(e0_[r]*scl);
    aw[row*72 + (lp*2 + 1)*16 + l16] = f2h(e1_[r]*scl);
  }
  __syncthreads();                                             // B3

  // ---- GEMM3-h0 (aw @ t3, o-cols w*64..w*64+31) ----
  #pragma unroll
  for (int kc3 = 0; kc3 < 2; ++kc3) {
    half8 a3[4];
    #pragma unroll
    for (int mt = 0; mt < 4; ++mt)
      a3[mt] = *(const half8*)(&aw[(mt*16 + l16)*72 + kc3*32 + quad*8]);
    #pragma unroll
    for (int ot = 0; ot < 2; ++ot) {
      half8 bf = *(const half8*)(t3f + ((size_t)(n*32 + w*4 + ot)*2 + kc3)*512 + lane*8);
      #pragma unroll
      for (int mt = 0; mt < 4; ++mt) acc[mt][ot] = mfma16(a3[mt], bf, acc[mt][ot]);
    }
  }

  // ---- epilogue h0: wave-private LDS transpose, 128B-line float4 bursts ----
  float* sc = scb + w*576;   // 16 x 36 f32 (2304 B per wave)
  #pragma unroll
  for (int mt = 0; mt < 4; ++mt) {
    #pragma unroll
    for (int ot = 0; ot < 2; ++ot)
      #pragma unroll
      for (int r = 0; r < 4; ++r)
        sc[(quad*4 + r)*36 + ot*16 + l16] = acc[mt][ot][r] + bias[ot];
    #pragma unroll
    for (int shot = 0; shot < 2; ++shot) {
      int row = shot*8 + (lane >> 3);
      float4 v = *(float4*)&sc[row*36 + (lane & 7)*4];
      *(float4*)&out[(size_t)(n*3136 + m0 + mt*16 + row)*512 + w*64 + (lane & 7)*4] = v;
    }
  }

  // ---- h1: GEMM4 (o-cols w*64+32..w*64+63) + GEMM3, then epilogue ----
  #pragma unroll
  for (int mt = 0; mt < 4; ++mt)
    #pragma unroll
    for (int ot = 0; ot < 2; ++ot) acc[mt][ot] = (f32x4){0.f, 0.f, 0.f, 0.f};
  #pragma unroll
  for (int kc = 0; kc < 8; ++kc) {
    half8 a[4];
    #pragma unroll
    for (int mt = 0; mt < 4; ++mt)
      a[mt] = *(const half8*)(&xs[(mt*16 + l16)*264 + kc*32 + quad*8]);
    #pragma unroll
    for (int ot = 0; ot < 2; ++ot) {
      half8 bf = *(const half8*)(Wdf + ((size_t)(w*4 + 2 + ot)*8 + kc)*512 + lane*8);
      #pragma unroll
      for (int mt = 0; mt < 4; ++mt) acc[mt][ot] = mfma16(a[mt], bf, acc[mt][ot]);
    }
  }
  #pragma unroll
  for (int kc3 = 0; kc3 < 2; ++kc3) {
    half8 a3[4];
    #pragma unroll
    for (int mt = 0; mt < 4; ++mt)
      a3[mt] = *(const half8*)(&aw[(mt*16 + l16)*72 + kc3*32 + quad*8]);
    #pragma unroll
    for (int ot = 0; ot < 2; ++ot) {
      half8 bf = *(const half8*)(t3f + ((size_t)(n*32 + w*4 + 2 + ot)*2 + kc3)*512 + lane*8);
      #pragma unroll
      for (int mt = 0; mt < 4; ++mt) acc[mt][ot] = mfma16(a3[mt], bf, acc[mt][ot]);
    }
  }
  #pragma unroll
  for (int mt = 0; mt < 4; ++mt) {
    #pragma unroll
    for (int ot = 0; ot < 2; ++ot)
      #pragma unroll
      for (int r = 0; r < 4; ++r)
        sc[(quad*4 + r)*36 + ot*16 + l16] = acc[mt][ot][r] + bias[2 + ot];
    #pragma unroll
    for (int shot = 0; shot < 2; ++shot) {
      int row = shot*8 + (lane >> 3);
      float4 v = *(float4*)&sc[row*36 + (lane & 7)*4];
      *(float4*)&out[(size_t)(n*3136 + m0 + mt*16 + row)*512 + w*64 + 32 + (lane & 7)*4] = v;
    }
  }
}

// ---------------------------------------------------------------------------
extern "C" void kernel_launch(void* const* d_in, const int* in_sizes, int n_in,
                              void* d_out, int out_size, void* d_ws, size_t ws_size,
                              hipStream_t stream) {
  const float* x  = (const float*)d_in[0];
  const float* t  = (const float*)d_in[1];
  const float* W1 = (const float*)d_in[2];
  const float* W2 = (const float*)d_in[3];
  const float* W3 = (const float*)d_in[4];
  const float* b3 = (const float*)d_in[5];
  const float* Wd = (const float*)d_in[6];
  const float* bd = (const float*)d_in[7];
  float* out = (float*)d_out;

  // workspace layout (bytes), ~2.75 MB total — all fragment-linear f16
  char* ws = (char*)d_ws;
  u16* W3f = (u16*)(ws + 0);        //  262144
  u16* Wdf = (u16*)(ws + 262144);   //  262144
  u16* tf  = (u16*)(ws + 524288);   //  524288
  u16* Gtf = (u16*)(ws + 1048576);  //  131072
  u16* mtf = (u16*)(ws + 1179648);  //  524288
  u16* t3f = (u16*)(ws + 1703936);  //  1048576  (end 2752512)

  hipLaunchKernelGGL(prep_kernel, dim3(2304), dim3(256), 0, stream,
                     W1, W2, W3, Wd, t, W3f, Wdf, tf, Gtf);
  hipLaunchKernelGGL(mt_t3_kernel, dim3(192), dim3(256), 0, stream,
                     tf, Gtf, W3f, b3, mtf, t3f);
  hipLaunchKernelGGL(main_kernel, dim3(784), dim3(512), 0, stream,
                     x, Wdf, mtf, t3f, bd, out);
}

// Round 4
// 203.024 us; speedup vs baseline: 1.3750x; 1.3750x over previous
//
#include <hip/hip_runtime.h>

// Projector: out[n,p,o] = x@Wd^T + bd + softmax_l((x@W1^T)·(t@W2^T)^T) @ (t@W3^T + b3)
// N=16, HW=3136, L=64, C_IN=256, C_OUT=512, D=256. fp32 in/out.
// R8: R6 structure + clean o-split (R7 retried WITHOUT the a[rg] runtime-
//   register-index spill that poisoned it; rule #20).
//   R6 combined regfile ~136 (64 VGPR + 72 AGPR) > 128 cliff -> 1 block/CU.
//   Split o in time: ONE acc[4][2] reused across halves (~104 combined regs)
//   -> 4 waves/SIMD -> 2 blocks/CU; block A's stage/stores overlap block B's
//   MFMA. GEMM2 kept standalone (rg only in address arithmetic).
//   Epilogue scratch in dedicated LDS (xs stays live for h1).
// Phases: stage -> B1 -> GEMM2 -> partials -> B2 -> merge/aw -> B3
//   -> [GEMM4h0+GEMM3h0 -> epi h0] -> [GEMM4h1+GEMM3h1 -> epi h1]. 3 barriers.
// LDS 62,464 B => 2 blocks/CU = 125 KB.

typedef unsigned short u16;
using half8 = __attribute__((ext_vector_type(8))) _Float16;
using f32x4 = __attribute__((ext_vector_type(4))) float;

__device__ __forceinline__ u16 f2h(float f) {
  _Float16 h = (_Float16)f;            // RNE
  union { _Float16 h; u16 u; } cv; cv.h = h;
  return cv.u;
}

__device__ __forceinline__ f32x4 mfma16(half8 a, half8 b, f32x4 c) {
  return __builtin_amdgcn_mfma_f32_16x16x32_f16(a, b, c, 0, 0, 0);
}

// ---------------------------------------------------------------------------
// K0: reblock W3/Wd/t to fragment-linear f16, and compute Gt = (W1^T W2)^T
// in f32 (Gt[c,e] = sum_d W1[d,c]*W2[d,e]), rounded once to f16 FL.
// FL: flat(row,k) = ((row/16)*8 + k/32)*512 + ((k/8)%4)*128 + (row%16)*8 + (k%8)
// ---------------------------------------------------------------------------
__global__ __launch_bounds__(256) void prep_kernel(
    const float* __restrict__ W1, const float* __restrict__ W2,
    const float* __restrict__ W3, const float* __restrict__ Wd,
    const float* __restrict__ t,
    u16* __restrict__ W3f, u16* __restrict__ Wdf, u16* __restrict__ tf,
    u16* __restrict__ Gtf) {
  int b = blockIdx.x, k = threadIdx.x;
  if (b < 2048) {
    const float* src; u16* dst; int row;
    if (b < 512)       { src = W3; dst = W3f; row = b; }
    else if (b < 1024) { src = Wd; dst = Wdf; row = b - 512; }
    else               { src = t;  dst = tf;  row = b - 1024; }
    float v = src[(size_t)row*256 + k];
    int flat = ((row >> 4)*8 + (k >> 5))*512 + ((k >> 3) & 3)*128 + (row & 15)*8 + (k & 7);
    dst[flat] = f2h(v);
  } else {
    // Gt row c = b-2048 (uniform per block); thread k = e (coalesced W2 reads)
    int c = b - 2048;
    float g = 0.f;
    #pragma unroll 16
    for (int d = 0; d < 256; ++d)
      g = fmaf(W1[d*256 + c], W2[d*256 + k], g);
    int flat = ((c >> 4)*8 + (k >> 5))*512 + ((k >> 3) & 3)*128 + (c & 15)*8 + (k & 7);
    Gtf[flat] = f2h(g);
  }
}

// ---------------------------------------------------------------------------
// K1: per-n small GEMMs, all operands FL, outputs written FL.
// blocks 0..63:   Mt[n,l,c] = sum_e t[n,l,e]*Gt[c,e]  -> mtf (rows=l, K=c=256)
// blocks 64..191: t3[n,o,l] = t@W3^T + b3             -> t3f (rows=o, K=l=64)
// ---------------------------------------------------------------------------
__global__ __launch_bounds__(256) void mt_t3_kernel(
    const u16* __restrict__ tf, const u16* __restrict__ Gtf,
    const u16* __restrict__ W3f, const float* __restrict__ b3,
    u16* __restrict__ mtf, u16* __restrict__ t3f) {
  const int tid = threadIdx.x, w = tid >> 6, lane = tid & 63;
  const int quad = lane >> 4, l16 = lane & 15;
  const int b = blockIdx.x;

  if (b < 64) {
    const int n = b >> 2, eb = b & 3;      // eb = c-quarter
    const int gc = eb*4 + w;               // c-row group (c0 = eb*64 + w*16)
    f32x4 acc[4];
    #pragma unroll
    for (int mt = 0; mt < 4; ++mt) acc[mt] = (f32x4){0.f, 0.f, 0.f, 0.f};
    #pragma unroll
    for (int kc = 0; kc < 8; ++kc) {
      half8 bf = *(const half8*)(Gtf + (gc*8 + kc)*512 + lane*8);
      #pragma unroll
      for (int mt = 0; mt < 4; ++mt) {
        half8 a = *(const half8*)(tf + ((n*4 + mt)*8 + kc)*512 + lane*8);
        acc[mt] = mfma16(a, bf, acc[mt]);
      }
    }
    // value at (l = mt*16+quad*4+r, c = eb*64+w*16+l16); write FL for GEMM2
    #pragma unroll
    for (int mt = 0; mt < 4; ++mt)
      #pragma unroll
      for (int r = 0; r < 4; ++r) {
        int flat = ((n*4 + mt)*8 + eb*2 + (w >> 1))*512
                 + ((w & 1)*2 + (l16 >> 3))*128 + (quad*4 + r)*8 + (l16 & 7);
        mtf[flat] = f2h(acc[mt][r]);
      }
  } else {
    const int b2 = b - 64;
    const int n = b2 >> 3, ob = b2 & 7;
    const int gW3 = ob*4 + w;          // o-row group (o0 = ob*64 + w*16)
    f32x4 acc[4];
    #pragma unroll
    for (int nt = 0; nt < 4; ++nt) acc[nt] = (f32x4){0.f, 0.f, 0.f, 0.f};
    #pragma unroll
    for (int kc = 0; kc < 8; ++kc) {
      half8 a = *(const half8*)(W3f + (gW3*8 + kc)*512 + lane*8);
      #pragma unroll
      for (int nt = 0; nt < 4; ++nt) {
        half8 bf = *(const half8*)(tf + ((n*4 + nt)*8 + kc)*512 + lane*8);
        acc[nt] = mfma16(a, bf, acc[nt]);
      }
    }
    // value at (o = ob*64+w*16+quad*4+r, l = nt*16+l16); write FL for GEMM3
    #pragma unroll
    for (int nt = 0; nt < 4; ++nt)
      #pragma unroll
      for (int r = 0; r < 4; ++r) {
        int o = ob*64 + w*16 + quad*4 + r;
        int flat = ((n*32 + ob*4 + w)*2 + (nt >> 1))*512
                 + ((nt & 1)*2 + (l16 >> 3))*128 + (quad*4 + r)*8 + (l16 & 7);
        t3f[flat] = f2h(acc[nt][r] + b3[o]);
      }
  }
}

// ---------------------------------------------------------------------------
// K2: main fused kernel. grid 784 = 16 n * 49 row-tiles of 64; 512 threads.
// smem carve (62,464 B):
//   [0, 33792):       xs 64 x 264 u16           (live until GEMM4-h1)
//   [33792, 43008):   aw 64 x 72 u16            (live until GEMM3-h1)
//   [43008, 44032):   parts 64 x 2 x {mx,ps} f32
//   [44032, 62464):   epi scratch, 8 waves x 16 x 36 f32 (wave-private)
// 3 barriers. ~104 combined regs -> 4 waves/SIMD -> 2 blocks/CU (125 KB LDS).
// ---------------------------------------------------------------------------
__global__ __launch_bounds__(512, 4) void main_kernel(
    const float* __restrict__ x, const u16* __restrict__ Wdf,
    const u16* __restrict__ mtf, const u16* __restrict__ t3f,
    const float* __restrict__ bd, float* __restrict__ out) {
  __shared__ __attribute__((aligned(16))) char smem[62464];
  u16* xs = (u16*)smem;                      // 64 x 264
  u16* aw = (u16*)(smem + 33792);            // 64 x 72
  float* parts = (float*)(smem + 43008);     // 64 x 2 x {mx, ps}
  float* scb = (float*)(smem + 44032);       // 8 x (16 x 36) f32

  const int bid = blockIdx.x;
  const int n  = bid / 49;
  const int pt = bid - n*49;
  const int m0 = pt * 64;
  const int tid = threadIdx.x, w = tid >> 6, lane = tid & 63;
  const int quad = lane >> 4, l16 = lane & 15;
  const int rg = w & 3;        // GEMM2 row-group (rows rg*16..rg*16+15)
  const int lp = w >> 2;       // GEMM2 l-pair (l-groups lp*2, lp*2+1)

  float bias[4];
  #pragma unroll
  for (int ot = 0; ot < 4; ++ot) bias[ot] = bd[w*64 + ot*16 + l16];

  // ---- stage x tile: 64x256 fp32 -> f16 LDS (coalesced float4) ----
  {
    const float4* xg = (const float4*)(x + (size_t)(n*3136 + m0)*256);
    #pragma unroll
    for (int it = 0; it < 8; ++it) {
      int idx = it*512 + tid;
      int r = idx >> 6, c4 = idx & 63;
      float4 v = xg[idx];
      ushort4 u;
      u.x = f2h(v.x); u.y = f2h(v.y); u.z = f2h(v.z); u.w = f2h(v.w);
      *(ushort4*)(&xs[r*264 + c4*4]) = u;
    }
  }
  __syncthreads();                                             // B1

  // ---- GEMM2: a[p,l] = xs @ Mt^T  (each wave: 16 rows x 32 l, K=256) ----
  // rg/lp appear only in ADDRESS arithmetic (no runtime register-array index).
  f32x4 acc2[2];
  acc2[0] = (f32x4){0.f, 0.f, 0.f, 0.f};
  acc2[1] = (f32x4){0.f, 0.f, 0.f, 0.f};
  #pragma unroll
  for (int kc = 0; kc < 8; ++kc) {
    half8 a = *(const half8*)(&xs[(rg*16 + l16)*264 + kc*32 + quad*8]);
    #pragma unroll
    for (int j = 0; j < 2; ++j) {
      half8 bf = *(const half8*)(mtf + ((size_t)(n*4 + lp*2 + j)*8 + kc)*512 + lane*8);
      acc2[j] = mfma16(a, bf, acc2[j]);
    }
  }

  // ---- softmax partials over this wave's 32 l-cols ----
  float mx_[4], ps_[4], e0_[4], e1_[4];
  #pragma unroll
  for (int r = 0; r < 4; ++r) {
    float s0 = acc2[0][r], s1 = acc2[1][r];
    float mx = fmaxf(s0, s1);
    #pragma unroll
    for (int off = 8; off >= 1; off >>= 1) mx = fmaxf(mx, __shfl_xor(mx, off, 64));
    float e0 = __expf(s0 - mx), e1 = __expf(s1 - mx);
    float ps = e0 + e1;
    #pragma unroll
    for (int off = 8; off >= 1; off >>= 1) ps += __shfl_xor(ps, off, 64);
    mx_[r] = mx; ps_[r] = ps; e0_[r] = e0; e1_[r] = e1;
    if (l16 == 0) {
      int row = rg*16 + quad*4 + r;
      parts[(row*2 + lp)*2]     = mx;
      parts[(row*2 + lp)*2 + 1] = ps;
    }
  }
  __syncthreads();                                             // B2

  // ---- combine partials (online-softmax merge), write aw ----
  #pragma unroll
  for (int r = 0; r < 4; ++r) {
    int row = rg*16 + quad*4 + r;
    float mxo = parts[(row*2 + (1 - lp))*2];
    float pso = parts[(row*2 + (1 - lp))*2 + 1];
    float g  = fmaxf(mx_[r], mxo);
    float sA = __expf(mx_[r] - g), sB = __expf(mxo - g);
    float inv = 1.0f / (ps_[r]*sA + pso*sB);
    float scl = sA * inv;
    aw[row*72 + (lp*2)*16 + l16]     = f2h(e0_[r]*scl);
    aw[row*72 + (lp*2 + 1)*16 + l16] = f2h(e1_[r]*scl);
  }
  __syncthreads();                                             // B3

  float* sc = scb + w*576;   // 16 x 36 f32 (2304 B per wave, wave-private)
  f32x4 acc[4][2];           // ONE 32-AGPR accumulator reused for both halves

  // ==== o-half 0: GEMM4 (xs@Wd^T, o w*64..+31) + GEMM3 (aw@t3) -> epi ====
  #pragma unroll
  for (int mt = 0; mt < 4; ++mt)
    #pragma unroll
    for (int ot = 0; ot < 2; ++ot) acc[mt][ot] = (f32x4){0.f, 0.f, 0.f, 0.f};
  #pragma unroll
  for (int kc = 0; kc < 8; ++kc) {
    half8 a[4];
    #pragma unroll
    for (int mt = 0; mt < 4; ++mt)
      a[mt] = *(const half8*)(&xs[(mt*16 + l16)*264 + kc*32 + quad*8]);
    #pragma unroll
    for (int ot = 0; ot < 2; ++ot) {
      half8 bf = *(const half8*)(Wdf + ((size_t)(w*4 + ot)*8 + kc)*512 + lane*8);
      #pragma unroll
      for (int mt = 0; mt < 4; ++mt) acc[mt][ot] = mfma16(a[mt], bf, acc[mt][ot]);
    }
  }
  #pragma unroll
  for (int kc3 = 0; kc3 < 2; ++kc3) {
    half8 a3[4];
    #pragma unroll
    for (int mt = 0; mt < 4; ++mt)
      a3[mt] = *(const half8*)(&aw[(mt*16 + l16)*72 + kc3*32 + quad*8]);
    #pragma unroll
    for (int ot = 0; ot < 2; ++ot) {
      half8 bf = *(const half8*)(t3f + ((size_t)(n*32 + w*4 + ot)*2 + kc3)*512 + lane*8);
      #pragma unroll
      for (int mt = 0; mt < 4; ++mt) acc[mt][ot] = mfma16(a3[mt], bf, acc[mt][ot]);
    }
  }
  #pragma unroll
  for (int mt = 0; mt < 4; ++mt) {
    #pragma unroll
    for (int ot = 0; ot < 2; ++ot)
      #pragma unroll
      for (int r = 0; r < 4; ++r)
        sc[(quad*4 + r)*36 + ot*16 + l16] = acc[mt][ot][r] + bias[ot];
    #pragma unroll
    for (int shot = 0; shot < 2; ++shot) {
      int row = shot*8 + (lane >> 3);
      float4 v = *(float4*)&sc[row*36 + (lane & 7)*4];
      *(float4*)&out[(size_t)(n*3136 + m0 + mt*16 + row)*512 + w*64 + (lane & 7)*4] = v;
    }
  }

  // ==== o-half 1: GEMM4 (o w*64+32..+63) + GEMM3 -> epi ====
  #pragma unroll
  for (int mt = 0; mt < 4; ++mt)
    #pragma unroll
    for (int ot = 0; ot < 2; ++ot) acc[mt][ot] = (f32x4){0.f, 0.f, 0.f, 0.f};
  #pragma unroll
  for (int kc = 0; kc < 8; ++kc) {
    half8 a[4];
    #pragma unroll
    for (int mt = 0; mt < 4; ++mt)
      a[mt] = *(const half8*)(&xs[(mt*16 + l16)*264 + kc*32 + quad*8]);
    #pragma unroll
    for (int ot = 0; ot < 2; ++ot) {
      half8 bf = *(const half8*)(Wdf + ((size_t)(w*4 + 2 + ot)*8 + kc)*512 + lane*8);
      #pragma unroll
      for (int mt = 0; mt < 4; ++mt) acc[mt][ot] = mfma16(a[mt], bf, acc[mt][ot]);
    }
  }
  #pragma unroll
  for (int kc3 = 0; kc3 < 2; ++kc3) {
    half8 a3[4];
    #pragma unroll
    for (int mt = 0; mt < 4; ++mt)
      a3[mt] = *(const half8*)(&aw[(mt*16 + l16)*72 + kc3*32 + quad*8]);
    #pragma unroll
    for (int ot = 0; ot < 2; ++ot) {
      half8 bf = *(const half8*)(t3f + ((size_t)(n*32 + w*4 + 2 + ot)*2 + kc3)*512 + lane*8);
      #pragma unroll
      for (int mt = 0; mt < 4; ++mt) acc[mt][ot] = mfma16(a3[mt], bf, acc[mt][ot]);
    }
  }
  #pragma unroll
  for (int mt = 0; mt < 4; ++mt) {
    #pragma unroll
    for (int ot = 0; ot < 2; ++ot)
      #pragma unroll
      for (int r = 0; r < 4; ++r)
        sc[(quad*4 + r)*36 + ot*16 + l16] = acc[mt][ot][r] + bias[2 + ot];
    #pragma unroll
    for (int shot = 0; shot < 2; ++shot) {
      int row = shot*8 + (lane >> 3);
      float4 v = *(float4*)&sc[row*36 + (lane & 7)*4];
      *(float4*)&out[(size_t)(n*3136 + m0 + mt*16 + row)*512 + w*64 + 32 + (lane & 7)*4] = v;
    }
  }
}

// ---------------------------------------------------------------------------
extern "C" void kernel_launch(void* const* d_in, const int* in_sizes, int n_in,
                              void* d_out, int out_size, void* d_ws, size_t ws_size,
                              hipStream_t stream) {
  const float* x  = (const float*)d_in[0];
  const float* t  = (const float*)d_in[1];
  const float* W1 = (const float*)d_in[2];
  const float* W2 = (const float*)d_in[3];
  const float* W3 = (const float*)d_in[4];
  const float* b3 = (const float*)d_in[5];
  const float* Wd = (const float*)d_in[6];
  const float* bd = (const float*)d_in[7];
  float* out = (float*)d_out;

  // workspace layout (bytes), ~2.75 MB total — all fragment-linear f16
  char* ws = (char*)d_ws;
  u16* W3f = (u16*)(ws + 0);        //  262144
  u16* Wdf = (u16*)(ws + 262144);   //  262144
  u16* tf  = (u16*)(ws + 524288);   //  524288
  u16* Gtf = (u16*)(ws + 1048576);  //  131072
  u16* mtf = (u16*)(ws + 1179648);  //  524288
  u16* t3f = (u16*)(ws + 1703936);  //  1048576  (end 2752512)

  hipLaunchKernelGGL(prep_kernel, dim3(2304), dim3(256), 0, stream,
                     W1, W2, W3, Wd, t, W3f, Wdf, tf, Gtf);
  hipLaunchKernelGGL(mt_t3_kernel, dim3(192), dim3(256), 0, stream,
                     tf, Gtf, W3f, b3, mtf, t3f);
  hipLaunchKernelGGL(main_kernel, dim3(784), dim3(512), 0, stream,
                     x, Wdf, mtf, t3f, bd, out);
}